// Round 9
// baseline (675.031 us; speedup 1.0000x reference)
//
#include <hip/hip_runtime.h>
#include <math.h>

// WaveNet (4,256,16384), 20 layers. Round 13 = round-12 (617us) +
//  (1) LDS-repacked coalesced f16 stores everywhere fragments used to
//      scatter 32B segments (gemm1 y1 measured 2.15x write-amplified:
//      WRITE 72MB for 33.5MB): layer phase-4 h store, first_conv h0
//      store, gemm mode-0 y1 store.
//  (2) flush merged as a block-local tail into layers 7/15/19 (pattern
//      numerically proven in the rounds-2-4 fused kernel): two-pass
//      n-halving reuses the layer's 37KB As/Bs so ALL layer dispatches
//      keep 4 blocks/CU; removes 3 serial dispatches. Tail epilogue
//      stores (Abuf/skr) also LDS-repacked.

#define T_LEN   16384
#define NB      4
#define BT      (NB * T_LEN)     // 65536
#define NLAYERS 20
#define SQH     0.70710678118654752440f

typedef _Float16 half8 __attribute__((ext_vector_type(8)));
typedef _Float16 half4 __attribute__((ext_vector_type(4)));
typedef float f32x4 __attribute__((ext_vector_type(4)));

__device__ inline f32x4 mfma16(half8 a, half8 b, f32x4 c) {
  return __builtin_amdgcn_mfma_f32_16x16x32_f16(a, b, c, 0, 0, 0);
}

// chunked XCD swizzle: physical block pb (XCD = pb%8 round-robin) -> logical
// lb such that consecutive logical blocks share an XCD chunk. nwg % 8 == 0.
__device__ __forceinline__ int xswz(int pb, int nwg) {
  return (pb & 7) * (nwg >> 3) + (pb >> 3);
}

// ---------------- weight packing (f16) ----------------
__global__ __launch_bounds__(256) void prep_pack(
    const float* __restrict__ Wf, const float* __restrict__ Wdil,
    const float* __restrict__ Wc, const float* __restrict__ Wskip,
    const float* __restrict__ Wout, const float* __restrict__ Wl1,
    const float* __restrict__ Wl2, const float* __restrict__ bdil,
    const float* __restrict__ bc, const float* __restrict__ bskip,
    _Float16* __restrict__ wdp, _Float16* __restrict__ wcp,
    _Float16* __restrict__ wop, _Float16* __restrict__ wskp,
    _Float16* __restrict__ wfp, _Float16* __restrict__ wl1p,
    _Float16* __restrict__ wl2p, float* __restrict__ bde,
    float* __restrict__ bsk)
{
  const float Q = 0.70710678118654752440f;
  const int WDP_E = 20 * 3 * 128 * 64;   // [l][tau][n][kc]
  const int WCP_E = 20 * 128 * 96;       // [l][n][kc pad96]
  const int WOP_E = 20 * 64 * 64;        // [l][n][kc]
  const int WSK_E = 256 * 1280;          // [n][l*64+kc], scale q^(1-l)
  const int WFP_E = 64 * 512;            // [n][tau*256+ci]
  const int WL_E  = 256 * 256;
  const int BDE_E = 20 * 128;
  const int BSK_E = 256;
  const int TOTAL = WDP_E + WCP_E + WOP_E + WSK_E + WFP_E + 2 * WL_E + BDE_E + BSK_E;
  for (int i = blockIdx.x * blockDim.x + threadIdx.x; i < TOTAL;
       i += gridDim.x * blockDim.x) {
    int j = i;
    if (j < WDP_E) {
      int l = j / (3 * 128 * 64); int r2 = j % (3 * 128 * 64);
      int tau = r2 / (128 * 64);  int r3 = r2 % (128 * 64);
      int n = r3 >> 6; int kc = r3 & 63;
      wdp[j] = (_Float16)Wdil[((l * 128 + n) * 64 + kc) * 3 + tau];
      continue;
    }
    j -= WDP_E;
    if (j < WCP_E) {
      int l = j / (128 * 96); int r2 = j % (128 * 96);
      int n = r2 / 96; int kc = r2 % 96;
      wcp[j] = (_Float16)(kc < 80 ? Wc[(l * 128 + n) * 80 + kc] : 0.f);
      continue;
    }
    j -= WCP_E;
    if (j < WOP_E) {
      int l = j >> 12; int r2 = j & 4095;
      int n = r2 >> 6; int kc = r2 & 63;
      wop[j] = (_Float16)Wout[(l * 64 + n) * 64 + kc];
      continue;
    }
    j -= WOP_E;
    if (j < WSK_E) {
      int n = j / 1280; int k = j % 1280;
      int l = k >> 6; int kc = k & 63;
      float f = (l == 0) ? 1.f : powf(Q, (float)(1 - l));
      wskp[j] = (_Float16)(Wskip[(l * 256 + n) * 64 + kc] * f);
      continue;
    }
    j -= WSK_E;
    if (j < WFP_E) {
      int n = j >> 9; int k = j & 511;
      int tau = k >> 8; int ci = k & 255;
      wfp[j] = (_Float16)Wf[(n * 256 + ci) * 2 + tau];
      continue;
    }
    j -= WFP_E;
    if (j < WL_E) { wl1p[j] = (_Float16)Wl1[j]; continue; }
    j -= WL_E;
    if (j < WL_E) { wl2p[j] = (_Float16)Wl2[j]; continue; }
    j -= WL_E;
    if (j < BDE_E) { bde[j] = bdil[j] + bc[j]; continue; }
    j -= BDE_E;
    {
      int n = j;
      float s = 0.f;
      for (int l = 0; l < NLAYERS; ++l) {
        float w = powf(Q, (float)(l == 0 ? 19 : 20 - l));
        s += bskip[l * 256 + n] * w;
      }
      bsk[n] = s;
    }
  }
}

// ------- x transpose, vectorized: (B,256,T) f32 -> (BT,256) f16 -----------
__global__ __launch_bounds__(256) void tr_x_kernel(
    const float* __restrict__ src, _Float16* __restrict__ dst)
{
  __shared__ float tile[32 * 132];
  const int lb = xswz(blockIdx.x, 4096);
  const int row_tile = lb >> 3, cb = lb & 7;
  const int bb = row_tile >> 7;
  const int t0 = (row_tile & 127) * 128;
  const int ch0 = cb * 32;
  {
    int ch = threadIdx.x >> 3, tq = (threadIdx.x & 7) * 16;
    const float4* s4 = (const float4*)(src + ((size_t)(bb * 256 + ch0 + ch)) * T_LEN + t0 + tq);
#pragma unroll
    for (int j = 0; j < 4; ++j)
      *(float4*)&tile[ch * 132 + tq + 4 * j] = s4[j];
  }
  __syncthreads();
  {
    int t = threadIdx.x >> 1, c16 = (threadIdx.x & 1) * 16;
    half8 h0, h1;
#pragma unroll
    for (int j = 0; j < 8; ++j) {
      h0[j] = (_Float16)tile[(c16 + j) * 132 + t];
      h1[j] = (_Float16)tile[(c16 + 8 + j) * 132 + t];
    }
    _Float16* o = dst + ((size_t)(bb * T_LEN + t0 + t)) * 256 + ch0 + c16;
    *(half8*)o = h0;
    *(half8*)(o + 8) = h1;
  }
}

// ---------------- transpose (B,C,T) f32 -> (BT,Cpad) f16 (c path) ---------
__global__ __launch_bounds__(256) void tr_kernel(
    const float* __restrict__ src, _Float16* __restrict__ dst, int C, int Cpad, int CB)
{
  __shared__ float tile[32 * 33];
  int lb = xswz(blockIdx.x, gridDim.x);
  int cb = lb % CB;
  int tb = (lb / CB) % (T_LEN / 32);
  int bb = lb / (CB * (T_LEN / 32));
  int t0 = tb * 32, ch0 = cb * 32;
  int tl = threadIdx.x & 31, cl = threadIdx.x >> 5;
#pragma unroll
  for (int i = 0; i < 4; ++i) {
    int ch = cl + 8 * i;
    float v = (ch0 + ch < C) ? src[((size_t)bb * C + ch0 + ch) * T_LEN + t0 + tl] : 0.f;
    tile[ch * 33 + tl] = v;
  }
  __syncthreads();
  int t = threadIdx.x >> 3;
  int c4 = (threadIdx.x & 7) * 4;
  half4 hv = {(_Float16)tile[(c4 + 0) * 33 + t], (_Float16)tile[(c4 + 1) * 33 + t],
              (_Float16)tile[(c4 + 2) * 33 + t], (_Float16)tile[(c4 + 3) * 33 + t]};
  *(half4*)&dst[((size_t)bb * T_LEN + t0 + t) * Cpad + ch0 + c4] = hv;
}

// ---------------- first conv: h0 = tanh(Wf*[x(t-1);x(t)] + bf), f16 out ----
__global__ __launch_bounds__(256, 4) void first_conv(
    const _Float16* __restrict__ xt, const _Float16* __restrict__ wfp,
    const float* __restrict__ bf, _Float16* __restrict__ h0)
{
  __shared__ _Float16 As[128 * 72];
  __shared__ _Float16 Bs[64 * 72];
  const int tid = threadIdx.x;
  const int lane = tid & 63, w = tid >> 6;
  const int wx = w & 1, wy = w >> 1;
  const int l15 = lane & 15, quad = lane >> 4;
  const int p0 = xswz(blockIdx.x, 512) * 128;
  const int b = p0 >> 14, t0 = p0 & (T_LEN - 1);
  const int r = tid >> 1, halfo = (tid & 1) * 32;

  f32x4 acc[4][2];
#pragma unroll
  for (int mi = 0; mi < 4; ++mi)
#pragma unroll
    for (int ni = 0; ni < 2; ++ni) { f32x4 z = {0.f, 0.f, 0.f, 0.f}; acc[mi][ni] = z; }

  for (int s = 0; s < 8; ++s) {
    int tau = s >> 2, ci0 = (s & 3) * 64;
    int ts = t0 + r - 1 + tau;
    if (ts >= 0) {
      const uint4* src = (const uint4*)(xt + ((size_t)(b * T_LEN + ts) * 256 + ci0 + halfo));
#pragma unroll
      for (int j = 0; j < 4; ++j) *(uint4*)&As[r * 72 + halfo + 8 * j] = src[j];
    } else {
      uint4 z = {0, 0, 0, 0};
#pragma unroll
      for (int j = 0; j < 4; ++j) *(uint4*)&As[r * 72 + halfo + 8 * j] = z;
    }
    if (tid < 128) {
      const uint4* s4 = (const uint4*)(wfp + ((size_t)r * 512 + tau * 256 + ci0 + halfo));
#pragma unroll
      for (int j = 0; j < 4; ++j) *(uint4*)&Bs[r * 72 + halfo + 8 * j] = s4[j];
    }
    __syncthreads();
#pragma unroll
    for (int kc = 0; kc < 2; ++kc) {
      const int k0 = kc * 32 + quad * 8;
      half8 af[4], bfr[2];
#pragma unroll
      for (int mi = 0; mi < 4; ++mi)
        af[mi] = *(const half8*)&As[(64 * wy + 16 * mi + l15) * 72 + k0];
#pragma unroll
      for (int ni = 0; ni < 2; ++ni)
        bfr[ni] = *(const half8*)&Bs[(32 * wx + 16 * ni + l15) * 72 + k0];
#pragma unroll
      for (int mi = 0; mi < 4; ++mi)
#pragma unroll
        for (int ni = 0; ni < 2; ++ni)
          acc[mi][ni] = mfma16(af[mi], bfr[ni], acc[mi][ni]);
    }
    __syncthreads();
  }
  // repack h0 tile into As (f16), then coalesced 64B/thread stores
#pragma unroll
  for (int mi = 0; mi < 4; ++mi)
#pragma unroll
    for (int ni = 0; ni < 2; ++ni) {
      int col = 32 * wx + 16 * ni + l15;
      int rowb = 64 * wy + 16 * mi + quad * 4;
      float bo = bf[col];
#pragma unroll
      for (int reg = 0; reg < 4; ++reg) {
        float v = acc[mi][ni][reg] + bo;
        float e = __expf(2.f * v);
        As[(rowb + reg) * 72 + col] = (_Float16)(1.f - 2.f * __builtin_amdgcn_rcpf(e + 1.f));
      }
    }
  __syncthreads();
  {
    int row = tid >> 1, co = (tid & 1) * 32;
    _Float16* o = h0 + ((size_t)(p0 + row)) * 64 + co;
    const uint4* s = (const uint4*)&As[row * 72 + co];
#pragma unroll
    for (int j = 0; j < 4; ++j) *(uint4*)(o + 8 * j) = s[j];
  }
}

// ---------------- one residual layer: 512 threads, 8 waves (2x4) -----------
// Round-0 structure (single As/Bs, 37KB LDS, 4 blocks/CU) + LDS-repacked h
// store + optional block-local skip-flush tail (fmode>=0) at l=7/15/19.
__global__ __launch_bounds__(512, 4) void layer_kernel(
    const _Float16* __restrict__ hprev, _Float16* __restrict__ hnext,
    const _Float16* __restrict__ ctp,
    const _Float16* __restrict__ wdp_l, const _Float16* __restrict__ wcp_l,
    const _Float16* __restrict__ wop_l,
    const float* __restrict__ bde_l, const float* __restrict__ bout_l,
    _Float16* __restrict__ zslot, int d, int last,
    const _Float16* __restrict__ zbuf, const _Float16* __restrict__ wskp,
    _Float16* __restrict__ Abuf, const float* __restrict__ bsk,
    _Float16* __restrict__ skr, int fl0, int fg, int fmode)
{
  __shared__ _Float16 smem[2 * 128 * 72];   // As | Bs (contiguous for tail Ts)
  __shared__ float bde_s[128];
  _Float16* As = smem;
  _Float16* Bs = smem + 128 * 72;

  const int tid = threadIdx.x;
  const int lane = tid & 63, w = tid >> 6;        // 8 waves
  const int wx = w & 1, wy = w >> 1;              // 2 (N) x 4 (M)
  const int l15 = lane & 15, quad = lane >> 4;
  const int p0 = xswz(blockIdx.x, 512) * 128;
  const int b = p0 >> 14, t0 = p0 & (T_LEN - 1);
  const int r2 = tid >> 2, qo = (tid & 3) * 16;   // staging: row, 16-elem chunk
  const int o8 = (tid & 3) * 8;                   // K=32 stage chunk

  if (tid < 128) bde_s[tid] = bde_l[tid];

  f32x4 acc[2][4];
#pragma unroll
  for (int mi = 0; mi < 2; ++mi)
#pragma unroll
    for (int ni = 0; ni < 4; ++ni) { f32x4 z = {0.f, 0.f, 0.f, 0.f}; acc[mi][ni] = z; }

  // K stages: h[t-2d], h[t-d], h[t] (64 each), cond[0:64], cond[64:96] (K=32)
  for (int s = 0; s < 5; ++s) {
    if (s < 3) {
      int ts = t0 + r2 - (2 - s) * d;
      if (ts >= 0) {
        const uint4* src = (const uint4*)(hprev + ((size_t)(b * T_LEN + ts) * 64 + qo));
        *(uint4*)&As[r2 * 72 + qo] = src[0];
        *(uint4*)&As[r2 * 72 + qo + 8] = src[1];
      } else {
        uint4 z4 = {0, 0, 0, 0};
        *(uint4*)&As[r2 * 72 + qo] = z4;
        *(uint4*)&As[r2 * 72 + qo + 8] = z4;
      }
      const uint4* sb = (const uint4*)(wdp_l + ((size_t)s * 8192 + r2 * 64 + qo));
      *(uint4*)&Bs[r2 * 72 + qo] = sb[0];
      *(uint4*)&Bs[r2 * 72 + qo + 8] = sb[1];
    } else if (s == 3) {
      const uint4* sa = (const uint4*)(ctp + ((size_t)(p0 + r2) * 96 + qo));
      *(uint4*)&As[r2 * 72 + qo] = sa[0];
      *(uint4*)&As[r2 * 72 + qo + 8] = sa[1];
      const uint4* sb = (const uint4*)(wcp_l + ((size_t)r2 * 96 + qo));
      *(uint4*)&Bs[r2 * 72 + qo] = sb[0];
      *(uint4*)&Bs[r2 * 72 + qo + 8] = sb[1];
    } else {  // s == 4: K=32 tail of cond
      *(uint4*)&As[r2 * 72 + o8] = *(const uint4*)(ctp + ((size_t)(p0 + r2) * 96 + 64 + o8));
      *(uint4*)&Bs[r2 * 72 + o8] = *(const uint4*)(wcp_l + ((size_t)r2 * 96 + 64 + o8));
    }
    __syncthreads();
    const int nkc = (s == 4) ? 1 : 2;
    for (int kc = 0; kc < nkc; ++kc) {
      const int k0 = kc * 32 + quad * 8;
      half8 af[2], bfr[4];
#pragma unroll
      for (int mi = 0; mi < 2; ++mi)
        af[mi] = *(const half8*)&As[(32 * wy + 16 * mi + l15) * 72 + k0];
#pragma unroll
      for (int ni = 0; ni < 4; ++ni) {
        int ncol = 32 * wx + 16 * (ni & 1) + 64 * (ni >> 1);  // ch and ch+64
        bfr[ni] = *(const half8*)&Bs[(ncol + l15) * 72 + k0];
      }
#pragma unroll
      for (int mi = 0; mi < 2; ++mi)
#pragma unroll
        for (int ni = 0; ni < 4; ++ni)
          acc[mi][ni] = mfma16(af[mi], bfr[ni], acc[mi][ni]);
    }
    __syncthreads();
  }

  // gate: z = tanh(y[ch]) * sigmoid(y[ch+64]) -> Zs (aliases As)
#pragma unroll
  for (int mi = 0; mi < 2; ++mi)
#pragma unroll
    for (int ni2 = 0; ni2 < 2; ++ni2) {
      int colb = 32 * wx + 16 * ni2 + l15;
      float ba = bde_s[colb], bb = bde_s[colb + 64];
#pragma unroll
      for (int reg = 0; reg < 4; ++reg) {
        float av = acc[mi][ni2][reg] + ba;
        float gv = acc[mi][ni2 + 2][reg] + bb;
        float ea = __expf(2.f * av);
        float th = 1.f - 2.f * __builtin_amdgcn_rcpf(ea + 1.f);
        float sg = __builtin_amdgcn_rcpf(1.f + __expf(-gv));
        As[(32 * wy + 16 * mi + quad * 4 + reg) * 72 + colb] = (_Float16)(th * sg);
      }
    }

  // stage W_out (64x64) into Bs (skip for the dead h of the last layer)
  if (!last && tid < 256) {
    int row = tid >> 2;
    const uint4* sb = (const uint4*)(wop_l + ((size_t)row * 64 + qo));
    *(uint4*)&Bs[row * 72 + qo] = sb[0];
    *(uint4*)&Bs[row * 72 + qo + 8] = sb[1];
  }
  __syncthreads();

  // z -> global ring slot (coalesced via As rows)
  {
    uint4 v0 = *(const uint4*)&As[r2 * 72 + qo];
    uint4 v1 = *(const uint4*)&As[r2 * 72 + qo + 8];
    uint4* dst = (uint4*)(zslot + ((size_t)(p0 + r2) * 64 + qo));
    dst[0] = v0; dst[1] = v1;
  }

  if (!last) {
    // phase 4: h_out = (Wout*z + b_out + h_in) * SQH  (h_in re-read from L2)
    f32x4 a4[2][2];
#pragma unroll
    for (int mi = 0; mi < 2; ++mi)
#pragma unroll
      for (int ni = 0; ni < 2; ++ni) { f32x4 z = {0.f, 0.f, 0.f, 0.f}; a4[mi][ni] = z; }
#pragma unroll
    for (int kc = 0; kc < 2; ++kc) {
      const int k0 = kc * 32 + quad * 8;
      half8 af[2], bfr[2];
#pragma unroll
      for (int mi = 0; mi < 2; ++mi)
        af[mi] = *(const half8*)&As[(32 * wy + 16 * mi + l15) * 72 + k0];
#pragma unroll
      for (int ni = 0; ni < 2; ++ni)
        bfr[ni] = *(const half8*)&Bs[(32 * wx + 16 * ni + l15) * 72 + k0];
#pragma unroll
      for (int mi = 0; mi < 2; ++mi)
#pragma unroll
        for (int ni = 0; ni < 2; ++ni)
          a4[mi][ni] = mfma16(af[mi], bfr[ni], a4[mi][ni]);
    }
    __syncthreads();   // all phase-4 As/Bs reads done before As overwrite
#pragma unroll
    for (int mi = 0; mi < 2; ++mi)
#pragma unroll
      for (int ni = 0; ni < 2; ++ni) {
        int col = 32 * wx + 16 * ni + l15;
        int rowb = 32 * wy + 16 * mi + quad * 4;
        float bo = bout_l[col];
        size_t base = ((size_t)p0 + rowb) * 64 + col;
#pragma unroll
        for (int reg = 0; reg < 4; ++reg) {
          float hv = (float)hprev[base + (size_t)64 * reg];
          As[(rowb + reg) * 72 + col] = (_Float16)((a4[mi][ni][reg] + bo + hv) * SQH);
        }
      }
    __syncthreads();
    {
      uint4 v0 = *(const uint4*)&As[r2 * 72 + qo];
      uint4 v1 = *(const uint4*)&As[r2 * 72 + qo + 8];
      uint4* dst = (uint4*)(hnext + ((size_t)(p0 + r2) * 64 + qo));
      dst[0] = v0; dst[1] = v1;
    }
  }

  // ---------------- block-local skip-flush tail (l = 7/15/19) -------------
  if (fmode >= 0) {
    __syncthreads();          // all As/Bs readers done before restaging
    __threadfence_block();    // own z-slot store -> own reload below
    f32x4 fac[2][2][4];       // [pass][mi][ni]
#pragma unroll
    for (int p = 0; p < 2; ++p)
#pragma unroll
      for (int mi = 0; mi < 2; ++mi)
#pragma unroll
        for (int ni = 0; ni < 4; ++ni) { f32x4 z = {0.f, 0.f, 0.f, 0.f}; fac[p][mi][ni] = z; }

#pragma unroll 1
    for (int j = 0; j < fg; ++j) {
      const int lj = fl0 + j;
      const _Float16* zsl = zbuf + (size_t)(lj & 7) * ((size_t)BT * 64);
      {  // stage z tile (As) and Wskip n-half 0 (Bs)
        const uint4* sa = (const uint4*)(zsl + ((size_t)(p0 + r2) * 64 + qo));
        *(uint4*)&As[r2 * 72 + qo] = sa[0];
        *(uint4*)&As[r2 * 72 + qo + 8] = sa[1];
        const uint4* sb = (const uint4*)(wskp + ((size_t)r2 * 1280 + lj * 64 + qo));
        *(uint4*)&Bs[r2 * 72 + qo] = sb[0];
        *(uint4*)&Bs[r2 * 72 + qo + 8] = sb[1];
      }
      __syncthreads();
#pragma unroll
      for (int kc = 0; kc < 2; ++kc) {
        const int k0 = kc * 32 + quad * 8;
        half8 af[2], bfr[4];
#pragma unroll
        for (int mi = 0; mi < 2; ++mi)
          af[mi] = *(const half8*)&As[(32 * wy + 16 * mi + l15) * 72 + k0];
#pragma unroll
        for (int ni = 0; ni < 4; ++ni)
          bfr[ni] = *(const half8*)&Bs[(64 * wx + 16 * ni + l15) * 72 + k0];
#pragma unroll
        for (int mi = 0; mi < 2; ++mi)
#pragma unroll
          for (int ni = 0; ni < 4; ++ni)
            fac[0][mi][ni] = mfma16(af[mi], bfr[ni], fac[0][mi][ni]);
      }
      __syncthreads();
      {  // stage Wskip n-half 1 (Bs); As (z) unchanged
        const uint4* sb = (const uint4*)(wskp + ((size_t)(128 + r2) * 1280 + lj * 64 + qo));
        *(uint4*)&Bs[r2 * 72 + qo] = sb[0];
        *(uint4*)&Bs[r2 * 72 + qo + 8] = sb[1];
      }
      __syncthreads();
#pragma unroll
      for (int kc = 0; kc < 2; ++kc) {
        const int k0 = kc * 32 + quad * 8;
        half8 af[2], bfr[4];
#pragma unroll
        for (int mi = 0; mi < 2; ++mi)
          af[mi] = *(const half8*)&As[(32 * wy + 16 * mi + l15) * 72 + k0];
#pragma unroll
        for (int ni = 0; ni < 4; ++ni)
          bfr[ni] = *(const half8*)&Bs[(64 * wx + 16 * ni + l15) * 72 + k0];
#pragma unroll
        for (int mi = 0; mi < 2; ++mi)
#pragma unroll
          for (int ni = 0; ni < 4; ++ni)
            fac[1][mi][ni] = mfma16(af[mi], bfr[ni], fac[1][mi][ni]);
      }
      __syncthreads();
    }

    // epilogue: LDS-repacked coalesced 256-col f16 rows, two 64-row halves
    const float Q19 = 0.0013810679320049757f;  // sqrt(0.5)^19
    _Float16* Ts = smem;                        // 64 x 264 f16 = 33.8KB
    _Float16* dbase = (fmode == 2) ? skr : Abuf;
#pragma unroll 1
    for (int h = 0; h < 2; ++h) {
      if ((wy >> 1) == h) {
#pragma unroll
        for (int p = 0; p < 2; ++p)
#pragma unroll
          for (int mi = 0; mi < 2; ++mi)
#pragma unroll
            for (int ni = 0; ni < 4; ++ni) {
              int col = p * 128 + 64 * wx + 16 * ni + l15;
              int rowb = 32 * wy + 16 * mi + quad * 4;
#pragma unroll
              for (int reg = 0; reg < 4; ++reg) {
                int row = rowb + reg;
                float v = fac[p][mi][ni][reg];
                if (fmode == 1) {
                  v += (float)Abuf[((size_t)(p0 + row)) * 256 + col];
                } else if (fmode == 2) {
                  v = (v + (float)Abuf[((size_t)(p0 + row)) * 256 + col]) * Q19 + bsk[col];
                  v = v > 0.f ? v : 0.f;
                }
                Ts[(row - 64 * h) * 264 + col] = (_Float16)v;
              }
            }
      }
      __syncthreads();
      {
        int lr = tid >> 3, co = (tid & 7) * 32;
        _Float16* o = dbase + ((size_t)(p0 + 64 * h + lr)) * 256 + co;
        const uint4* s = (const uint4*)&Ts[lr * 264 + co];
#pragma unroll
        for (int jj = 0; jj < 4; ++jj) *(uint4*)(o + 8 * jj) = s[jj];
      }
      __syncthreads();
    }
  }
}

// ---------------- generic 256x256 GEMM (last1 / last2) -------------------
// mode 0: dst f16 row-major (BT,256), relu, LDS-repacked coalesced store.
// mode 1: dst f32 (B,256,T), +bias, coalesced via LDS transpose.
__global__ __launch_bounds__(256, 4) void gemm256(
    const _Float16* __restrict__ Asrc, const _Float16* __restrict__ Bp,
    const float* __restrict__ bias, void* __restrict__ dst, int mode)
{
  __shared__ _Float16 smem[2 * 128 * 72];
  _Float16* As = smem;
  _Float16* Bs = smem + 128 * 72;
  const int tid = threadIdx.x;
  const int lane = tid & 63, w = tid >> 6;
  const int wx = w & 1, wy = w >> 1;
  const int l15 = lane & 15, quad = lane >> 4;
  const int p0 = xswz(blockIdx.x, 512) * 128;
  const int n0 = blockIdx.y * 128;
  const int r = tid >> 1, halfo = (tid & 1) * 32;

  f32x4 acc[4][4];
#pragma unroll
  for (int mi = 0; mi < 4; ++mi)
#pragma unroll
    for (int ni = 0; ni < 4; ++ni) { f32x4 z = {0.f, 0.f, 0.f, 0.f}; acc[mi][ni] = z; }

  for (int c4 = 0; c4 < 4; ++c4) {
    int k0g = c4 * 64;
    const uint4* sa = (const uint4*)(Asrc + ((size_t)(p0 + r) * 256 + k0g + halfo));
#pragma unroll
    for (int jj = 0; jj < 4; ++jj) *(uint4*)&As[r * 72 + halfo + 8 * jj] = sa[jj];
    const uint4* sb = (const uint4*)(Bp + ((size_t)(n0 + r) * 256 + k0g + halfo));
#pragma unroll
    for (int jj = 0; jj < 4; ++jj) *(uint4*)&Bs[r * 72 + halfo + 8 * jj] = sb[jj];
    __syncthreads();
#pragma unroll
    for (int kc = 0; kc < 2; ++kc) {
      const int k0 = kc * 32 + quad * 8;
      half8 af[4], bfr[4];
#pragma unroll
      for (int mi = 0; mi < 4; ++mi)
        af[mi] = *(const half8*)&As[(64 * wy + 16 * mi + l15) * 72 + k0];
#pragma unroll
      for (int ni = 0; ni < 4; ++ni)
        bfr[ni] = *(const half8*)&Bs[(64 * wx + 16 * ni + l15) * 72 + k0];
#pragma unroll
      for (int mi = 0; mi < 4; ++mi)
#pragma unroll
        for (int ni = 0; ni < 4; ++ni)
          acc[mi][ni] = mfma16(af[mi], bfr[ni], acc[mi][ni]);
    }
    __syncthreads();
  }
  if (mode == 0) {
    // LDS-repacked coalesced f16 store (two 64-row halves, full 256B rows)
    _Float16* Ts = smem;     // 64 x 136 f16
#pragma unroll 1
    for (int h = 0; h < 2; ++h) {
      if (wy == h) {
#pragma unroll
        for (int mi = 0; mi < 4; ++mi)
#pragma unroll
          for (int ni = 0; ni < 4; ++ni) {
            int col = 64 * wx + 16 * ni + l15;
            int lr = 16 * mi + quad * 4;
            float bv = bias[n0 + col];
#pragma unroll
            for (int reg = 0; reg < 4; ++reg) {
              float v = acc[mi][ni][reg] + bv;
              Ts[(lr + reg) * 136 + col] = (_Float16)(v > 0.f ? v : 0.f);
            }
          }
      }
      __syncthreads();
      {
        int lr = tid >> 2, co = (tid & 3) * 32;
        _Float16* o = (_Float16*)dst + ((size_t)(p0 + 64 * h + lr)) * 256 + n0 + co;
        const uint4* s = (const uint4*)&Ts[lr * 136 + co];
#pragma unroll
        for (int jj = 0; jj < 4; ++jj) *(uint4*)(o + 8 * jj) = s[jj];
      }
      __syncthreads();
    }
  } else {
    // transposed coalesced store: two passes of 64 columns through LDS
    float* Ts = (float*)smem;       // 64 x 132 floats = 33792 B
    const int b = p0 >> 14, t0g = p0 & (T_LEN - 1);
    for (int pass = 0; pass < 2; ++pass) {
      if (wx == pass) {
#pragma unroll
        for (int mi = 0; mi < 4; ++mi)
#pragma unroll
          for (int ni = 0; ni < 4; ++ni) {
            int col_l = 16 * ni + l15;
            float bv = bias[n0 + 64 * pass + col_l];
            int tl = 64 * wy + 16 * mi + quad * 4;
#pragma unroll
            for (int reg = 0; reg < 4; ++reg)
              Ts[col_l * 132 + tl + reg] = acc[mi][ni][reg] + bv;
          }
      }
      __syncthreads();
      {
        int col_l = tid >> 2;
        int tq = (tid & 3) * 32;
        float* o = (float*)dst + ((size_t)b * 256 + n0 + 64 * pass + col_l) * T_LEN + t0g + tq;
#pragma unroll
        for (int j = 0; j < 8; ++j)
          *(float4*)(o + 4 * j) = *(const float4*)&Ts[col_l * 132 + tq + 4 * j];
      }
      __syncthreads();
    }
  }
}

extern "C" void kernel_launch(void* const* d_in, const int* in_sizes, int n_in,
                              void* d_out, int out_size, void* d_ws, size_t ws_size,
                              hipStream_t stream)
{
  const float* x     = (const float*)d_in[0];
  const float* c     = (const float*)d_in[1];
  const float* Wf    = (const float*)d_in[2];
  const float* bf    = (const float*)d_in[3];
  const float* Wdil  = (const float*)d_in[4];
  const float* bdil  = (const float*)d_in[5];
  const float* Wc    = (const float*)d_in[6];
  const float* bc    = (const float*)d_in[7];
  const float* Wskip = (const float*)d_in[8];
  const float* bskip = (const float*)d_in[9];
  const float* Wout  = (const float*)d_in[10];
  const float* bout  = (const float*)d_in[11];
  const float* Wl1   = (const float*)d_in[12];
  const float* bl1   = (const float*)d_in[13];
  const float* Wl2   = (const float*)d_in[14];
  const float* bl2   = (const float*)d_in[15];

  char* base = (char*)d_ws;
  // 8-slot z ring (64 MiB). Aliases: xt = slots 0-3 (consumed by first_conv
  // before layer 0 writes slot 0); skr = slots 4-7 (l=19 tail reads slots
  // 0-3 only, so writing skr there is safe); y1 = slots 0-3 (free after the
  // l=19 tail). Abuf (f16) lives in d_out, dead before gemm256 #2 writes
  // the final f32 output there.
  _Float16* zbuf = (_Float16*)base;
  _Float16* xt   = zbuf;
  _Float16* skr  = zbuf + (size_t)4 * BT * 64;
  _Float16* y1   = zbuf;
  _Float16* ctp  = (_Float16*)(base + 67108864);   // BT*96 f16 = 12.58 MB
  _Float16* hA   = (_Float16*)(base + 79691776);   // BT*64 f16 = 8.39 MB
  _Float16* hB   = (_Float16*)(base + 88080384);
  _Float16* wdp  = (_Float16*)(base + 96468992);
  _Float16* wcp  = wdp  + (size_t)20 * 3 * 128 * 64;
  _Float16* wop  = wcp  + (size_t)20 * 128 * 96;
  _Float16* wskp = wop  + (size_t)20 * 64 * 64;
  _Float16* wfp  = wskp + (size_t)256 * 1280;
  _Float16* wl1p = wfp  + (size_t)64 * 512;
  _Float16* wl2p = wl1p + (size_t)256 * 256;
  float*    bde  = (float*)(wl2p + (size_t)256 * 256);
  float*    bsk  = bde + 20 * 128;
  _Float16* Abuf = (_Float16*)d_out;               // f16 skip accumulator

  prep_pack<<<2048, 256, 0, stream>>>(Wf, Wdil, Wc, Wskip, Wout, Wl1, Wl2,
                                      bdil, bc, bskip,
                                      wdp, wcp, wop, wskp, wfp, wl1p, wl2p,
                                      bde, bsk);
  tr_x_kernel<<<4096, 256, 0, stream>>>(x, xt);
  tr_kernel<<<NB * (T_LEN / 32) * 3, 256, 0, stream>>>(c, ctp, 80, 96, 3);
  first_conv<<<512, 256, 0, stream>>>(xt, wfp, bf, hA);

  const _Float16* hin = hA;
  _Float16* hout = hB;
  for (int l = 0; l < NLAYERS; ++l) {
    int d = 1 << (l % 10);
    int fm  = (l == 7) ? 0 : (l == 15) ? 1 : (l == NLAYERS - 1) ? 2 : -1;
    int fl0 = (l == 7) ? 0 : (l == 15) ? 8 : 16;
    int fg  = (l == NLAYERS - 1) ? 4 : 8;
    layer_kernel<<<512, 512, 0, stream>>>(
        hin, hout, ctp,
        wdp + (size_t)l * 3 * 128 * 64, wcp + (size_t)l * 128 * 96,
        wop + (size_t)l * 64 * 64, bde + l * 128, bout + l * 64,
        zbuf + (size_t)(l & 7) * BT * 64, d, (l == NLAYERS - 1) ? 1 : 0,
        zbuf, wskp, Abuf, bsk, skr, fl0, fg, fm);
    _Float16* tmp = (_Float16*)hin; hin = hout; hout = tmp;
  }
  gemm256<<<dim3(512, 2), 256, 0, stream>>>(skr, wl1p, bl1, (void*)y1, 0);
  gemm256<<<dim3(512, 2), 256, 0, stream>>>(y1, wl2p, bl2, d_out, 1);
}

// Round 10
// 625.696 us; speedup vs baseline: 1.0788x; 1.0788x over previous
//
#include <hip/hip_runtime.h>
#include <math.h>

// WaveNet (4,256,16384), 20 layers. Round 14. Round-9 post-mortem: merging
// the flush into layers 7/15/19 serialized the two n-halves (78us vs
// 20+25us split) -> REVERTED to round-8's separate 512-thread flush_kernel
// (617us structure). KEPT the LDS-repacked coalesced f16 stores targeting
// the measured 2.15x write amplification (gemm1 y1: 72MB written for a
// 33.5MB tensor): first_conv h0 store, layer phase-4 h store, gemm256
// mode-0 y1 store.

#define T_LEN   16384
#define NB      4
#define BT      (NB * T_LEN)     // 65536
#define NLAYERS 20
#define SQH     0.70710678118654752440f

typedef _Float16 half8 __attribute__((ext_vector_type(8)));
typedef _Float16 half4 __attribute__((ext_vector_type(4)));
typedef float f32x4 __attribute__((ext_vector_type(4)));

__device__ inline f32x4 mfma16(half8 a, half8 b, f32x4 c) {
  return __builtin_amdgcn_mfma_f32_16x16x32_f16(a, b, c, 0, 0, 0);
}

// chunked XCD swizzle: physical block pb (XCD = pb%8 round-robin) -> logical
// lb such that consecutive logical blocks share an XCD chunk. nwg % 8 == 0.
__device__ __forceinline__ int xswz(int pb, int nwg) {
  return (pb & 7) * (nwg >> 3) + (pb >> 3);
}

// ---------------- weight packing (f16) ----------------
__global__ __launch_bounds__(256) void prep_pack(
    const float* __restrict__ Wf, const float* __restrict__ Wdil,
    const float* __restrict__ Wc, const float* __restrict__ Wskip,
    const float* __restrict__ Wout, const float* __restrict__ Wl1,
    const float* __restrict__ Wl2, const float* __restrict__ bdil,
    const float* __restrict__ bc, const float* __restrict__ bskip,
    _Float16* __restrict__ wdp, _Float16* __restrict__ wcp,
    _Float16* __restrict__ wop, _Float16* __restrict__ wskp,
    _Float16* __restrict__ wfp, _Float16* __restrict__ wl1p,
    _Float16* __restrict__ wl2p, float* __restrict__ bde,
    float* __restrict__ bsk)
{
  const float Q = 0.70710678118654752440f;
  const int WDP_E = 20 * 3 * 128 * 64;   // [l][tau][n][kc]
  const int WCP_E = 20 * 128 * 96;       // [l][n][kc pad96]
  const int WOP_E = 20 * 64 * 64;        // [l][n][kc]
  const int WSK_E = 256 * 1280;          // [n][l*64+kc], scale q^(1-l)
  const int WFP_E = 64 * 512;            // [n][tau*256+ci]
  const int WL_E  = 256 * 256;
  const int BDE_E = 20 * 128;
  const int BSK_E = 256;
  const int TOTAL = WDP_E + WCP_E + WOP_E + WSK_E + WFP_E + 2 * WL_E + BDE_E + BSK_E;
  for (int i = blockIdx.x * blockDim.x + threadIdx.x; i < TOTAL;
       i += gridDim.x * blockDim.x) {
    int j = i;
    if (j < WDP_E) {
      int l = j / (3 * 128 * 64); int r2 = j % (3 * 128 * 64);
      int tau = r2 / (128 * 64);  int r3 = r2 % (128 * 64);
      int n = r3 >> 6; int kc = r3 & 63;
      wdp[j] = (_Float16)Wdil[((l * 128 + n) * 64 + kc) * 3 + tau];
      continue;
    }
    j -= WDP_E;
    if (j < WCP_E) {
      int l = j / (128 * 96); int r2 = j % (128 * 96);
      int n = r2 / 96; int kc = r2 % 96;
      wcp[j] = (_Float16)(kc < 80 ? Wc[(l * 128 + n) * 80 + kc] : 0.f);
      continue;
    }
    j -= WCP_E;
    if (j < WOP_E) {
      int l = j >> 12; int r2 = j & 4095;
      int n = r2 >> 6; int kc = r2 & 63;
      wop[j] = (_Float16)Wout[(l * 64 + n) * 64 + kc];
      continue;
    }
    j -= WOP_E;
    if (j < WSK_E) {
      int n = j / 1280; int k = j % 1280;
      int l = k >> 6; int kc = k & 63;
      float f = (l == 0) ? 1.f : powf(Q, (float)(1 - l));
      wskp[j] = (_Float16)(Wskip[(l * 256 + n) * 64 + kc] * f);
      continue;
    }
    j -= WSK_E;
    if (j < WFP_E) {
      int n = j >> 9; int k = j & 511;
      int tau = k >> 8; int ci = k & 255;
      wfp[j] = (_Float16)Wf[(n * 256 + ci) * 2 + tau];
      continue;
    }
    j -= WFP_E;
    if (j < WL_E) { wl1p[j] = (_Float16)Wl1[j]; continue; }
    j -= WL_E;
    if (j < WL_E) { wl2p[j] = (_Float16)Wl2[j]; continue; }
    j -= WL_E;
    if (j < BDE_E) { bde[j] = bdil[j] + bc[j]; continue; }
    j -= BDE_E;
    {
      int n = j;
      float s = 0.f;
      for (int l = 0; l < NLAYERS; ++l) {
        float w = powf(Q, (float)(l == 0 ? 19 : 20 - l));
        s += bskip[l * 256 + n] * w;
      }
      bsk[n] = s;
    }
  }
}

// ------- x transpose, vectorized: (B,256,T) f32 -> (BT,256) f16 -----------
__global__ __launch_bounds__(256) void tr_x_kernel(
    const float* __restrict__ src, _Float16* __restrict__ dst)
{
  __shared__ float tile[32 * 132];
  const int lb = xswz(blockIdx.x, 4096);
  const int row_tile = lb >> 3, cb = lb & 7;
  const int bb = row_tile >> 7;
  const int t0 = (row_tile & 127) * 128;
  const int ch0 = cb * 32;
  {
    int ch = threadIdx.x >> 3, tq = (threadIdx.x & 7) * 16;
    const float4* s4 = (const float4*)(src + ((size_t)(bb * 256 + ch0 + ch)) * T_LEN + t0 + tq);
#pragma unroll
    for (int j = 0; j < 4; ++j)
      *(float4*)&tile[ch * 132 + tq + 4 * j] = s4[j];
  }
  __syncthreads();
  {
    int t = threadIdx.x >> 1, c16 = (threadIdx.x & 1) * 16;
    half8 h0, h1;
#pragma unroll
    for (int j = 0; j < 8; ++j) {
      h0[j] = (_Float16)tile[(c16 + j) * 132 + t];
      h1[j] = (_Float16)tile[(c16 + 8 + j) * 132 + t];
    }
    _Float16* o = dst + ((size_t)(bb * T_LEN + t0 + t)) * 256 + ch0 + c16;
    *(half8*)o = h0;
    *(half8*)(o + 8) = h1;
  }
}

// ---------------- transpose (B,C,T) f32 -> (BT,Cpad) f16 (c path) ---------
__global__ __launch_bounds__(256) void tr_kernel(
    const float* __restrict__ src, _Float16* __restrict__ dst, int C, int Cpad, int CB)
{
  __shared__ float tile[32 * 33];
  int lb = xswz(blockIdx.x, gridDim.x);
  int cb = lb % CB;
  int tb = (lb / CB) % (T_LEN / 32);
  int bb = lb / (CB * (T_LEN / 32));
  int t0 = tb * 32, ch0 = cb * 32;
  int tl = threadIdx.x & 31, cl = threadIdx.x >> 5;
#pragma unroll
  for (int i = 0; i < 4; ++i) {
    int ch = cl + 8 * i;
    float v = (ch0 + ch < C) ? src[((size_t)bb * C + ch0 + ch) * T_LEN + t0 + tl] : 0.f;
    tile[ch * 33 + tl] = v;
  }
  __syncthreads();
  int t = threadIdx.x >> 3;
  int c4 = (threadIdx.x & 7) * 4;
  half4 hv = {(_Float16)tile[(c4 + 0) * 33 + t], (_Float16)tile[(c4 + 1) * 33 + t],
              (_Float16)tile[(c4 + 2) * 33 + t], (_Float16)tile[(c4 + 3) * 33 + t]};
  *(half4*)&dst[((size_t)bb * T_LEN + t0 + t) * Cpad + ch0 + c4] = hv;
}

// ---------------- first conv: h0 = tanh(Wf*[x(t-1);x(t)] + bf), f16 out ----
__global__ __launch_bounds__(256, 4) void first_conv(
    const _Float16* __restrict__ xt, const _Float16* __restrict__ wfp,
    const float* __restrict__ bf, _Float16* __restrict__ h0)
{
  __shared__ _Float16 As[128 * 72];
  __shared__ _Float16 Bs[64 * 72];
  const int tid = threadIdx.x;
  const int lane = tid & 63, w = tid >> 6;
  const int wx = w & 1, wy = w >> 1;
  const int l15 = lane & 15, quad = lane >> 4;
  const int p0 = xswz(blockIdx.x, 512) * 128;
  const int b = p0 >> 14, t0 = p0 & (T_LEN - 1);
  const int r = tid >> 1, halfo = (tid & 1) * 32;

  f32x4 acc[4][2];
#pragma unroll
  for (int mi = 0; mi < 4; ++mi)
#pragma unroll
    for (int ni = 0; ni < 2; ++ni) { f32x4 z = {0.f, 0.f, 0.f, 0.f}; acc[mi][ni] = z; }

  for (int s = 0; s < 8; ++s) {
    int tau = s >> 2, ci0 = (s & 3) * 64;
    int ts = t0 + r - 1 + tau;
    if (ts >= 0) {
      const uint4* src = (const uint4*)(xt + ((size_t)(b * T_LEN + ts) * 256 + ci0 + halfo));
#pragma unroll
      for (int j = 0; j < 4; ++j) *(uint4*)&As[r * 72 + halfo + 8 * j] = src[j];
    } else {
      uint4 z = {0, 0, 0, 0};
#pragma unroll
      for (int j = 0; j < 4; ++j) *(uint4*)&As[r * 72 + halfo + 8 * j] = z;
    }
    if (tid < 128) {
      const uint4* s4 = (const uint4*)(wfp + ((size_t)r * 512 + tau * 256 + ci0 + halfo));
#pragma unroll
      for (int j = 0; j < 4; ++j) *(uint4*)&Bs[r * 72 + halfo + 8 * j] = s4[j];
    }
    __syncthreads();
#pragma unroll
    for (int kc = 0; kc < 2; ++kc) {
      const int k0 = kc * 32 + quad * 8;
      half8 af[4], bfr[2];
#pragma unroll
      for (int mi = 0; mi < 4; ++mi)
        af[mi] = *(const half8*)&As[(64 * wy + 16 * mi + l15) * 72 + k0];
#pragma unroll
      for (int ni = 0; ni < 2; ++ni)
        bfr[ni] = *(const half8*)&Bs[(32 * wx + 16 * ni + l15) * 72 + k0];
#pragma unroll
      for (int mi = 0; mi < 4; ++mi)
#pragma unroll
        for (int ni = 0; ni < 2; ++ni)
          acc[mi][ni] = mfma16(af[mi], bfr[ni], acc[mi][ni]);
    }
    __syncthreads();
  }
  // repack h0 tile into As (f16), then coalesced 64B/thread stores
#pragma unroll
  for (int mi = 0; mi < 4; ++mi)
#pragma unroll
    for (int ni = 0; ni < 2; ++ni) {
      int col = 32 * wx + 16 * ni + l15;
      int rowb = 64 * wy + 16 * mi + quad * 4;
      float bo = bf[col];
#pragma unroll
      for (int reg = 0; reg < 4; ++reg) {
        float v = acc[mi][ni][reg] + bo;
        float e = __expf(2.f * v);
        As[(rowb + reg) * 72 + col] = (_Float16)(1.f - 2.f * __builtin_amdgcn_rcpf(e + 1.f));
      }
    }
  __syncthreads();
  {
    int row = tid >> 1, co = (tid & 1) * 32;
    _Float16* o = h0 + ((size_t)(p0 + row)) * 64 + co;
    const uint4* s = (const uint4*)&As[row * 72 + co];
#pragma unroll
    for (int j = 0; j < 4; ++j) *(uint4*)(o + 8 * j) = s[j];
  }
}

// ---------------- one residual layer: 512 threads, 8 waves (2x4) -----------
// Round-0 structure (single As/Bs, 37KB LDS, 4 blocks/CU); LDS-repacked
// coalesced h store; last-layer dead phase-4 skipped.
__global__ __launch_bounds__(512, 4) void layer_kernel(
    const _Float16* __restrict__ hprev, _Float16* __restrict__ hnext,
    const _Float16* __restrict__ ctp,
    const _Float16* __restrict__ wdp_l, const _Float16* __restrict__ wcp_l,
    const _Float16* __restrict__ wop_l,
    const float* __restrict__ bde_l, const float* __restrict__ bout_l,
    _Float16* __restrict__ zslot, int d, int last)
{
  __shared__ _Float16 As[128 * 72];   // A operand; becomes Zs after gate
  __shared__ _Float16 Bs[128 * 72];
  __shared__ float bde_s[128];

  const int tid = threadIdx.x;
  const int lane = tid & 63, w = tid >> 6;        // 8 waves
  const int wx = w & 1, wy = w >> 1;              // 2 (N) x 4 (M)
  const int l15 = lane & 15, quad = lane >> 4;
  const int p0 = xswz(blockIdx.x, 512) * 128;
  const int b = p0 >> 14, t0 = p0 & (T_LEN - 1);
  const int r2 = tid >> 2, qo = (tid & 3) * 16;   // staging: row, 16-elem chunk
  const int o8 = (tid & 3) * 8;                   // K=32 stage chunk

  if (tid < 128) bde_s[tid] = bde_l[tid];

  f32x4 acc[2][4];
#pragma unroll
  for (int mi = 0; mi < 2; ++mi)
#pragma unroll
    for (int ni = 0; ni < 4; ++ni) { f32x4 z = {0.f, 0.f, 0.f, 0.f}; acc[mi][ni] = z; }

  // K stages: h[t-2d], h[t-d], h[t] (64 each), cond[0:64], cond[64:96] (K=32)
  for (int s = 0; s < 5; ++s) {
    if (s < 3) {
      int ts = t0 + r2 - (2 - s) * d;
      if (ts >= 0) {
        const uint4* src = (const uint4*)(hprev + ((size_t)(b * T_LEN + ts) * 64 + qo));
        *(uint4*)&As[r2 * 72 + qo] = src[0];
        *(uint4*)&As[r2 * 72 + qo + 8] = src[1];
      } else {
        uint4 z4 = {0, 0, 0, 0};
        *(uint4*)&As[r2 * 72 + qo] = z4;
        *(uint4*)&As[r2 * 72 + qo + 8] = z4;
      }
      const uint4* sb = (const uint4*)(wdp_l + ((size_t)s * 8192 + r2 * 64 + qo));
      *(uint4*)&Bs[r2 * 72 + qo] = sb[0];
      *(uint4*)&Bs[r2 * 72 + qo + 8] = sb[1];
    } else if (s == 3) {
      const uint4* sa = (const uint4*)(ctp + ((size_t)(p0 + r2) * 96 + qo));
      *(uint4*)&As[r2 * 72 + qo] = sa[0];
      *(uint4*)&As[r2 * 72 + qo + 8] = sa[1];
      const uint4* sb = (const uint4*)(wcp_l + ((size_t)r2 * 96 + qo));
      *(uint4*)&Bs[r2 * 72 + qo] = sb[0];
      *(uint4*)&Bs[r2 * 72 + qo + 8] = sb[1];
    } else {  // s == 4: K=32 tail of cond
      *(uint4*)&As[r2 * 72 + o8] = *(const uint4*)(ctp + ((size_t)(p0 + r2) * 96 + 64 + o8));
      *(uint4*)&Bs[r2 * 72 + o8] = *(const uint4*)(wcp_l + ((size_t)r2 * 96 + 64 + o8));
    }
    __syncthreads();
    const int nkc = (s == 4) ? 1 : 2;
    for (int kc = 0; kc < nkc; ++kc) {
      const int k0 = kc * 32 + quad * 8;
      half8 af[2], bfr[4];
#pragma unroll
      for (int mi = 0; mi < 2; ++mi)
        af[mi] = *(const half8*)&As[(32 * wy + 16 * mi + l15) * 72 + k0];
#pragma unroll
      for (int ni = 0; ni < 4; ++ni) {
        int ncol = 32 * wx + 16 * (ni & 1) + 64 * (ni >> 1);  // ch and ch+64
        bfr[ni] = *(const half8*)&Bs[(ncol + l15) * 72 + k0];
      }
#pragma unroll
      for (int mi = 0; mi < 2; ++mi)
#pragma unroll
        for (int ni = 0; ni < 4; ++ni)
          acc[mi][ni] = mfma16(af[mi], bfr[ni], acc[mi][ni]);
    }
    __syncthreads();
  }

  // gate: z = tanh(y[ch]) * sigmoid(y[ch+64]) -> Zs (aliases As)
#pragma unroll
  for (int mi = 0; mi < 2; ++mi)
#pragma unroll
    for (int ni2 = 0; ni2 < 2; ++ni2) {
      int colb = 32 * wx + 16 * ni2 + l15;
      float ba = bde_s[colb], bb = bde_s[colb + 64];
#pragma unroll
      for (int reg = 0; reg < 4; ++reg) {
        float av = acc[mi][ni2][reg] + ba;
        float gv = acc[mi][ni2 + 2][reg] + bb;
        float ea = __expf(2.f * av);
        float th = 1.f - 2.f * __builtin_amdgcn_rcpf(ea + 1.f);
        float sg = __builtin_amdgcn_rcpf(1.f + __expf(-gv));
        As[(32 * wy + 16 * mi + quad * 4 + reg) * 72 + colb] = (_Float16)(th * sg);
      }
    }

  // stage W_out (64x64) into Bs (skip for the dead h of the last layer)
  if (!last && tid < 256) {
    int row = tid >> 2;
    const uint4* sb = (const uint4*)(wop_l + ((size_t)row * 64 + qo));
    *(uint4*)&Bs[row * 72 + qo] = sb[0];
    *(uint4*)&Bs[row * 72 + qo + 8] = sb[1];
  }
  __syncthreads();

  // z -> global ring slot (coalesced)
  {
    uint4 v0 = *(const uint4*)&As[r2 * 72 + qo];
    uint4 v1 = *(const uint4*)&As[r2 * 72 + qo + 8];
    uint4* dst = (uint4*)(zslot + ((size_t)(p0 + r2) * 64 + qo));
    dst[0] = v0; dst[1] = v1;
  }

  if (last) return;

  // phase 4: h_out = (Wout*z + b_out + h_in) * SQH  (h_in re-read from L2)
  f32x4 a4[2][2];
#pragma unroll
  for (int mi = 0; mi < 2; ++mi)
#pragma unroll
    for (int ni = 0; ni < 2; ++ni) { f32x4 z = {0.f, 0.f, 0.f, 0.f}; a4[mi][ni] = z; }
#pragma unroll
  for (int kc = 0; kc < 2; ++kc) {
    const int k0 = kc * 32 + quad * 8;
    half8 af[2], bfr[2];
#pragma unroll
    for (int mi = 0; mi < 2; ++mi)
      af[mi] = *(const half8*)&As[(32 * wy + 16 * mi + l15) * 72 + k0];
#pragma unroll
    for (int ni = 0; ni < 2; ++ni)
      bfr[ni] = *(const half8*)&Bs[(32 * wx + 16 * ni + l15) * 72 + k0];
#pragma unroll
    for (int mi = 0; mi < 2; ++mi)
#pragma unroll
      for (int ni = 0; ni < 2; ++ni)
        a4[mi][ni] = mfma16(af[mi], bfr[ni], a4[mi][ni]);
  }
  __syncthreads();   // all phase-4 As/Bs reads done before As overwrite
#pragma unroll
  for (int mi = 0; mi < 2; ++mi)
#pragma unroll
    for (int ni = 0; ni < 2; ++ni) {
      int col = 32 * wx + 16 * ni + l15;
      int rowb = 32 * wy + 16 * mi + quad * 4;
      float bo = bout_l[col];
      size_t base = ((size_t)p0 + rowb) * 64 + col;
#pragma unroll
      for (int reg = 0; reg < 4; ++reg) {
        float hv = (float)hprev[base + (size_t)64 * reg];
        As[(rowb + reg) * 72 + col] = (_Float16)((a4[mi][ni][reg] + bo + hv) * SQH);
      }
    }
  __syncthreads();
  {
    uint4 v0 = *(const uint4*)&As[r2 * 72 + qo];
    uint4 v1 = *(const uint4*)&As[r2 * 72 + qo + 8];
    uint4* dst = (uint4*)(hnext + ((size_t)(p0 + r2) * 64 + qo));
    dst[0] = v0; dst[1] = v1;
  }
}

// ---------------- deferred skip flush (512 threads, both n-halves) --------
// z tile staged ONCE in LDS, shared by both 128-col halves.
// mode 0: Abuf = acc   mode 1: Abuf += acc   mode 2: skr = relu((acc+Abuf)*q^19+bsk)
__global__ __launch_bounds__(512, 4) void flush_kernel(
    const _Float16* __restrict__ zbuf, const _Float16* __restrict__ wskp,
    _Float16* __restrict__ Abuf, const float* __restrict__ bsk,
    _Float16* __restrict__ skr, int l0, int g, int mode)
{
  __shared__ _Float16 As[128 * 72];
  __shared__ _Float16 Bs0[128 * 72];
  __shared__ _Float16 Bs1[128 * 72];
  const int tid = threadIdx.x;
  const int half = tid >> 8;
  _Float16* Bsh = half ? Bs1 : Bs0;
  const int tloc = tid & 255;
  const int lane = tloc & 63, w4 = tloc >> 6;
  const int wx = w4 & 1, wy = w4 >> 1;
  const int l15 = lane & 15, quad = lane >> 4;
  const int p0 = xswz(blockIdx.x, 512) * 128;
  const int n0 = half * 128;
  const int r = tloc >> 1, halfo = (tloc & 1) * 32;

  f32x4 acc[4][4];
#pragma unroll
  for (int mi = 0; mi < 4; ++mi)
#pragma unroll
    for (int ni = 0; ni < 4; ++ni) { f32x4 z = {0.f, 0.f, 0.f, 0.f}; acc[mi][ni] = z; }

#pragma unroll 1
  for (int j = 0; j < g; ++j) {
    const int lj = l0 + j;
    const _Float16* zsl = zbuf + (size_t)(lj & 7) * ((size_t)BT * 64);
    if (half == 0) {
      const uint4* sa = (const uint4*)(zsl + ((size_t)(p0 + r) * 64 + halfo));
#pragma unroll
      for (int jj = 0; jj < 4; ++jj) *(uint4*)&As[r * 72 + halfo + 8 * jj] = sa[jj];
    }
    const uint4* sb = (const uint4*)(wskp + ((size_t)(n0 + r) * 1280 + lj * 64 + halfo));
#pragma unroll
    for (int jj = 0; jj < 4; ++jj) *(uint4*)&Bsh[r * 72 + halfo + 8 * jj] = sb[jj];
    __syncthreads();
#pragma unroll
    for (int kc = 0; kc < 2; ++kc) {
      const int k0 = kc * 32 + quad * 8;
      half8 af[4], bfr[4];
#pragma unroll
      for (int mi = 0; mi < 4; ++mi)
        af[mi] = *(const half8*)&As[(64 * wy + 16 * mi + l15) * 72 + k0];
#pragma unroll
      for (int ni = 0; ni < 4; ++ni)
        bfr[ni] = *(const half8*)&Bsh[(64 * wx + 16 * ni + l15) * 72 + k0];
#pragma unroll
      for (int mi = 0; mi < 4; ++mi)
#pragma unroll
        for (int ni = 0; ni < 4; ++ni)
          acc[mi][ni] = mfma16(af[mi], bfr[ni], acc[mi][ni]);
    }
    __syncthreads();
  }
  const float Q19 = 0.0013810679320049757f;  // sqrt(0.5)^19
#pragma unroll
  for (int mi = 0; mi < 4; ++mi)
#pragma unroll
    for (int ni = 0; ni < 4; ++ni) {
      int col = n0 + 64 * wx + 16 * ni + l15;
      int rowb = 64 * wy + 16 * mi + quad * 4;
      size_t base = ((size_t)p0 + rowb) * 256 + col;
      if (mode == 2) {
        float bb = bsk[col];
#pragma unroll
        for (int reg = 0; reg < 4; ++reg) {
          float v = (acc[mi][ni][reg] + (float)Abuf[base + (size_t)256 * reg]) * Q19 + bb;
          skr[base + (size_t)256 * reg] = (_Float16)(v > 0.f ? v : 0.f);
        }
      } else if (mode == 1) {
#pragma unroll
        for (int reg = 0; reg < 4; ++reg) {
          size_t a = base + (size_t)256 * reg;
          Abuf[a] = (_Float16)((float)Abuf[a] + acc[mi][ni][reg]);
        }
      } else {
#pragma unroll
        for (int reg = 0; reg < 4; ++reg)
          Abuf[base + (size_t)256 * reg] = (_Float16)acc[mi][ni][reg];
      }
    }
}

// ---------------- generic 256x256 GEMM (last1 / last2) -------------------
// mode 0: dst f16 row-major (BT,256), relu, LDS-repacked coalesced store.
// mode 1: dst f32 (B,256,T), +bias, coalesced via LDS transpose.
__global__ __launch_bounds__(256, 4) void gemm256(
    const _Float16* __restrict__ Asrc, const _Float16* __restrict__ Bp,
    const float* __restrict__ bias, void* __restrict__ dst, int mode)
{
  __shared__ _Float16 smem[2 * 128 * 72];
  _Float16* As = smem;
  _Float16* Bs = smem + 128 * 72;
  const int tid = threadIdx.x;
  const int lane = tid & 63, w = tid >> 6;
  const int wx = w & 1, wy = w >> 1;
  const int l15 = lane & 15, quad = lane >> 4;
  const int p0 = xswz(blockIdx.x, 512) * 128;
  const int n0 = blockIdx.y * 128;
  const int r = tid >> 1, halfo = (tid & 1) * 32;

  f32x4 acc[4][4];
#pragma unroll
  for (int mi = 0; mi < 4; ++mi)
#pragma unroll
    for (int ni = 0; ni < 4; ++ni) { f32x4 z = {0.f, 0.f, 0.f, 0.f}; acc[mi][ni] = z; }

  for (int c4 = 0; c4 < 4; ++c4) {
    int k0g = c4 * 64;
    const uint4* sa = (const uint4*)(Asrc + ((size_t)(p0 + r) * 256 + k0g + halfo));
#pragma unroll
    for (int jj = 0; jj < 4; ++jj) *(uint4*)&As[r * 72 + halfo + 8 * jj] = sa[jj];
    const uint4* sb = (const uint4*)(Bp + ((size_t)(n0 + r) * 256 + k0g + halfo));
#pragma unroll
    for (int jj = 0; jj < 4; ++jj) *(uint4*)&Bs[r * 72 + halfo + 8 * jj] = sb[jj];
    __syncthreads();
#pragma unroll
    for (int kc = 0; kc < 2; ++kc) {
      const int k0 = kc * 32 + quad * 8;
      half8 af[4], bfr[4];
#pragma unroll
      for (int mi = 0; mi < 4; ++mi)
        af[mi] = *(const half8*)&As[(64 * wy + 16 * mi + l15) * 72 + k0];
#pragma unroll
      for (int ni = 0; ni < 4; ++ni)
        bfr[ni] = *(const half8*)&Bs[(64 * wx + 16 * ni + l15) * 72 + k0];
#pragma unroll
      for (int mi = 0; mi < 4; ++mi)
#pragma unroll
        for (int ni = 0; ni < 4; ++ni)
          acc[mi][ni] = mfma16(af[mi], bfr[ni], acc[mi][ni]);
    }
    __syncthreads();
  }
  if (mode == 0) {
    // LDS-repacked coalesced f16 store (two 64-row halves, full 256B rows)
    _Float16* Ts = smem;     // 64 x 136 f16
#pragma unroll 1
    for (int h = 0; h < 2; ++h) {
      if (wy == h) {
#pragma unroll
        for (int mi = 0; mi < 4; ++mi)
#pragma unroll
          for (int ni = 0; ni < 4; ++ni) {
            int col = 64 * wx + 16 * ni + l15;
            int lr = 16 * mi + quad * 4;
            float bv = bias[n0 + col];
#pragma unroll
            for (int reg = 0; reg < 4; ++reg) {
              float v = acc[mi][ni][reg] + bv;
              Ts[(lr + reg) * 136 + col] = (_Float16)(v > 0.f ? v : 0.f);
            }
          }
      }
      __syncthreads();
      {
        int lr = tid >> 2, co = (tid & 3) * 32;
        _Float16* o = (_Float16*)dst + ((size_t)(p0 + 64 * h + lr)) * 256 + n0 + co;
        const uint4* s = (const uint4*)&Ts[lr * 136 + co];
#pragma unroll
        for (int jj = 0; jj < 4; ++jj) *(uint4*)(o + 8 * jj) = s[jj];
      }
      __syncthreads();
    }
  } else {
    // transposed coalesced store: two passes of 64 columns through LDS
    float* Ts = (float*)smem;       // 64 x 132 floats = 33792 B
    const int b = p0 >> 14, t0g = p0 & (T_LEN - 1);
    for (int pass = 0; pass < 2; ++pass) {
      if (wx == pass) {
#pragma unroll
        for (int mi = 0; mi < 4; ++mi)
#pragma unroll
          for (int ni = 0; ni < 4; ++ni) {
            int col_l = 16 * ni + l15;
            float bv = bias[n0 + 64 * pass + col_l];
            int tl = 64 * wy + 16 * mi + quad * 4;
#pragma unroll
            for (int reg = 0; reg < 4; ++reg)
              Ts[col_l * 132 + tl + reg] = acc[mi][ni][reg] + bv;
          }
      }
      __syncthreads();
      {
        int col_l = tid >> 2;
        int tq = (tid & 3) * 32;
        float* o = (float*)dst + ((size_t)b * 256 + n0 + 64 * pass + col_l) * T_LEN + t0g + tq;
#pragma unroll
        for (int j = 0; j < 8; ++j)
          *(float4*)(o + 4 * j) = *(const float4*)&Ts[col_l * 132 + tq + 4 * j];
      }
      __syncthreads();
    }
  }
}

extern "C" void kernel_launch(void* const* d_in, const int* in_sizes, int n_in,
                              void* d_out, int out_size, void* d_ws, size_t ws_size,
                              hipStream_t stream)
{
  const float* x     = (const float*)d_in[0];
  const float* c     = (const float*)d_in[1];
  const float* Wf    = (const float*)d_in[2];
  const float* bf    = (const float*)d_in[3];
  const float* Wdil  = (const float*)d_in[4];
  const float* bdil  = (const float*)d_in[5];
  const float* Wc    = (const float*)d_in[6];
  const float* bc    = (const float*)d_in[7];
  const float* Wskip = (const float*)d_in[8];
  const float* bskip = (const float*)d_in[9];
  const float* Wout  = (const float*)d_in[10];
  const float* bout  = (const float*)d_in[11];
  const float* Wl1   = (const float*)d_in[12];
  const float* bl1   = (const float*)d_in[13];
  const float* Wl2   = (const float*)d_in[14];
  const float* bl2   = (const float*)d_in[15];

  char* base = (char*)d_ws;
  // 8-slot z ring (64 MiB). Aliases: xt = slots 0-3 (consumed by first_conv
  // before layer 0 writes slot 0); skr = slots 4-7 (free after flush2);
  // y1 = slots 0-3 (free after flush3). Abuf (f16) lives in d_out, dead
  // before gemm256 #2 writes the final f32 output there.
  _Float16* zbuf = (_Float16*)base;
  _Float16* xt   = zbuf;
  _Float16* skr  = zbuf + (size_t)4 * BT * 64;
  _Float16* y1   = zbuf;
  _Float16* ctp  = (_Float16*)(base + 67108864);   // BT*96 f16 = 12.58 MB
  _Float16* hA   = (_Float16*)(base + 79691776);   // BT*64 f16 = 8.39 MB
  _Float16* hB   = (_Float16*)(base + 88080384);
  _Float16* wdp  = (_Float16*)(base + 96468992);
  _Float16* wcp  = wdp  + (size_t)20 * 3 * 128 * 64;
  _Float16* wop  = wcp  + (size_t)20 * 128 * 96;
  _Float16* wskp = wop  + (size_t)20 * 64 * 64;
  _Float16* wfp  = wskp + (size_t)256 * 1280;
  _Float16* wl1p = wfp  + (size_t)64 * 512;
  _Float16* wl2p = wl1p + (size_t)256 * 256;
  float*    bde  = (float*)(wl2p + (size_t)256 * 256);
  float*    bsk  = bde + 20 * 128;
  _Float16* Abuf = (_Float16*)d_out;               // f16 skip accumulator

  prep_pack<<<2048, 256, 0, stream>>>(Wf, Wdil, Wc, Wskip, Wout, Wl1, Wl2,
                                      bdil, bc, bskip,
                                      wdp, wcp, wop, wskp, wfp, wl1p, wl2p,
                                      bde, bsk);
  tr_x_kernel<<<4096, 256, 0, stream>>>(x, xt);
  tr_kernel<<<NB * (T_LEN / 32) * 3, 256, 0, stream>>>(c, ctp, 80, 96, 3);
  first_conv<<<512, 256, 0, stream>>>(xt, wfp, bf, hA);

  const _Float16* hin = hA;
  _Float16* hout = hB;
  for (int l = 0; l < NLAYERS; ++l) {
    int d = 1 << (l % 10);
    layer_kernel<<<512, 512, 0, stream>>>(
        hin, hout, ctp,
        wdp + (size_t)l * 3 * 128 * 64, wcp + (size_t)l * 128 * 96,
        wop + (size_t)l * 64 * 64, bde + l * 128, bout + l * 64,
        zbuf + (size_t)(l & 7) * BT * 64, d, (l == NLAYERS - 1) ? 1 : 0);
    _Float16* tmp = (_Float16*)hin; hin = hout; hout = tmp;
    if (l == 7)  flush_kernel<<<512, 512, 0, stream>>>(zbuf, wskp, Abuf, bsk, skr, 0, 8, 0);
    if (l == 15) flush_kernel<<<512, 512, 0, stream>>>(zbuf, wskp, Abuf, bsk, skr, 8, 8, 1);
    if (l == 19) flush_kernel<<<512, 512, 0, stream>>>(zbuf, wskp, Abuf, bsk, skr, 16, 4, 2);
  }
  gemm256<<<dim3(512, 2), 256, 0, stream>>>(skr, wl1p, bl1, (void*)y1, 0);
  gemm256<<<dim3(512, 2), 256, 0, stream>>>(y1, wl2p, bl2, d_out, 1);
}